// Round 10
// baseline (167.352 us; speedup 1.0000x reference)
//
#include <hip/hip_runtime.h>
#include <hip/hip_fp16.h>
#include <math.h>

#define NQ 10
#define NL 4
#define NA (NQ * NL)
#define PI_F 3.14159265358979323846f
#define ELEMS 4

typedef _Float16 h2 __attribute__((ext_vector_type(2)));

// ---------- packed-f16 complex helpers; amp layout: bits[15:0]=re, [31:16]=im ----------
// cmul_sg<SR,SI>(c,s) = (SR*c.re, SI*c.im) complex-multiplied with s. (HW-validated R4/R7)
template <int SR, int SI>
__device__ __forceinline__ unsigned cmul_sg(unsigned c, unsigned s) {
  unsigned d;
  if constexpr (SR > 0) {
    asm("v_pk_mul_f16 %0, %1, %2 op_sel_hi:[0,1]" : "=v"(d) : "v"(c), "v"(s));
  } else {
    asm("v_pk_mul_f16 %0, %1, %2 op_sel_hi:[0,1] neg_lo:[1,0] neg_hi:[1,0]"
        : "=v"(d) : "v"(c), "v"(s));
  }
  if constexpr (SI > 0) {
    asm("v_pk_fma_f16 %0, %1, %2, %0 op_sel:[1,1,0] op_sel_hi:[1,0,1] neg_lo:[1,0,0]"
        : "+v"(d) : "v"(c), "v"(s));
  } else {
    asm("v_pk_fma_f16 %0, %1, %2, %0 op_sel:[1,1,0] op_sel_hi:[1,0,1] neg_hi:[1,0,0]"
        : "+v"(d) : "v"(c), "v"(s));
  }
  return d;
}

template <int SR, int SI>
__device__ __forceinline__ unsigned cfma_sg(unsigned c, unsigned s, unsigned acc) {
  unsigned d;
  if constexpr (SR > 0) {
    asm("v_pk_fma_f16 %0, %1, %2, %3 op_sel_hi:[0,1,1]"
        : "=v"(d) : "v"(c), "v"(s), "v"(acc));
  } else {
    asm("v_pk_fma_f16 %0, %1, %2, %3 op_sel_hi:[0,1,1] neg_lo:[1,0,0] neg_hi:[1,0,0]"
        : "=v"(d) : "v"(c), "v"(s), "v"(acc));
  }
  if constexpr (SI > 0) {
    asm("v_pk_fma_f16 %0, %1, %2, %0 op_sel:[1,1,0] op_sel_hi:[1,0,1] neg_lo:[1,0,0]"
        : "+v"(d) : "v"(c), "v"(s));
  } else {
    asm("v_pk_fma_f16 %0, %1, %2, %0 op_sel:[1,1,0] op_sel_hi:[1,0,1] neg_hi:[1,0,0]"
        : "+v"(d) : "v"(c), "v"(s));
  }
  return d;
}

// ---------- lane-crossing: masks 1,2 quad_perm DPP; 8 row_ror:8 DPP;
// 4,16 ds_swizzle; 32 __shfl_xor (ds_permute). Split keeps VALU/DS balanced. ----------
template <int MASK>
__device__ __forceinline__ int ishfl_xor(int v) {
  if constexpr (MASK == 1) {
    return __builtin_amdgcn_update_dpp(v, v, 0xB1, 0xF, 0xF, true);
  } else if constexpr (MASK == 2) {
    return __builtin_amdgcn_update_dpp(v, v, 0x4E, 0xF, 0xF, true);
  } else if constexpr (MASK == 4) {
    return __builtin_amdgcn_ds_swizzle(v, 0x101F);
  } else if constexpr (MASK == 8) {
    return __builtin_amdgcn_update_dpp(v, v, 0x128, 0xF, 0xF, true);
  } else if constexpr (MASK == 16) {
    return __builtin_amdgcn_ds_swizzle(v, 0x401F);
  } else {
    return __shfl_xor(v, MASK, 64);
  }
}

template <int MASK>
__device__ __forceinline__ float fshfl_xor(float v) {
  return __int_as_float(ishfl_xor<MASK>(__float_as_int(v)));
}

__device__ __forceinline__ unsigned readlane_u(unsigned v, int l) {
  return (unsigned)__builtin_amdgcn_readlane((int)v, l);
}

__device__ __forceinline__ float wave_sum_h(float v) {
  v += fshfl_xor<1>(v);
  v += fshfl_xor<2>(v);
  v += fshfl_xor<4>(v);
  v += fshfl_xor<8>(v);
  v += fshfl_xor<16>(v);
  v += fshfl_xor<32>(v);
  return v;
}

// Round-to-nearest f16 pack (cvt_pkrtz is RTZ -> R6's 1.5% norm contraction).
__device__ __forceinline__ unsigned pack_h2_rtn(float re, float im) {
  return (unsigned)__half_as_ushort(__float2half(re)) |
         ((unsigned)__half_as_ushort(__float2half(im)) << 16);
}

// Cross gate on lane bit LB, ELEMS elements interleaved.
// A = bit?conj(u00):u00 (im sign bit31); B = bit?-re(u01):u01 (re sign bit15).
template <int LB>
__device__ __forceinline__ void cross_gateN(unsigned (&sv)[ELEMS][16],
                                            const unsigned (&u00)[ELEMS],
                                            const unsigned (&u01)[ELEMS],
                                            int lane) {
  const bool bit = (lane & (1 << LB)) != 0;
  unsigned A[ELEMS], B[ELEMS];
#pragma unroll
  for (int e = 0; e < ELEMS; ++e) {
    A[e] = bit ? (u00[e] ^ 0x80000000u) : u00[e];
    B[e] = bit ? (u01[e] ^ 0x00008000u) : u01[e];
  }
#pragma unroll
  for (int r = 0; r < 16; ++r) {
#pragma unroll
    for (int e = 0; e < ELEMS; ++e) {
      unsigned p = (unsigned)ishfl_xor<(1 << LB)>((int)sv[e][r]);
      sv[e][r] = cfma_sg<1, 1>(B[e], p, cmul_sg<1, 1>(A[e], sv[e][r]));
    }
  }
}

// Register-local gate on reg bit RB, ELEMS elements interleaved.
template <int RB>
__device__ __forceinline__ void local_gateN(unsigned (&sv)[ELEMS][16],
                                            const unsigned (&u00)[ELEMS],
                                            const unsigned (&u01)[ELEMS]) {
#pragma unroll
  for (int rlo = 0; rlo < 16; ++rlo) {
    if (rlo & (1 << RB)) continue;
    const int rhi = rlo | (1 << RB);
#pragma unroll
    for (int e = 0; e < ELEMS; ++e) {
      unsigned lo = sv[e][rlo], hi = sv[e][rhi];
      sv[e][rlo] = cfma_sg<1, 1>(u01[e], hi, cmul_sg<1, 1>(u00[e], lo));
      sv[e][rhi] = cfma_sg<1, -1>(u00[e], hi, cmul_sg<-1, 1>(u01[e], lo));
    }
  }
}

// One wave simulates ELEMS=4 batch elements (register-interleaved).
// 16384/4 = 4096 waves = 1024 blocks = exactly 4 blocks/CU under (256,4):
// single resident generation, no drain tail.
// State index i = lane*16 + r. Wire q at bit (9-q): wires 0..5 -> lane bits
// 5..0, wires 6..9 -> reg bits 3..0.
// launch_bounds(256,4): 128-VGPR cap; sv[4][16]=64 + temps ~ 105, no spill.
// ((256,8) caps at 64 and spills — R8: WRITE_SIZE 0.64->27 MB.)
__global__ __launch_bounds__(256, 4) void qsim_kernel(
    const float* __restrict__ x, const float* __restrict__ w,
    float* __restrict__ out, int batch) {
  const int lane = threadIdx.x & 63;
  const int wv = blockIdx.x * (blockDim.x >> 6) + (threadIdx.x >> 6);
  const int permSrc = lane ^ (lane >> 1);  // composed CNOT(q,q+1), q=0..4

  // weight-only gate factors: lane j<40 owns gate j = l*10+q
  float Pr = 0.f, Pi = 0.f, Qr = 0.f, Qi = 0.f;
  if (lane < NA) {
    float w0 = w[2 * lane], w1 = w[2 * lane + 1];
    float sphi, cphi, sw, cw;
    sincosf(0.5f * w0, &sphi, &cphi);
    sincosf(0.5f * w1, &sw, &cw);
    Pr = cw * cphi; Pi = -cw * sphi;  // P = cos(w1/2) e^{-i w0/2}
    Qr = sw * cphi; Qi = sw * sphi;   // Q = sin(w1/2) e^{+i w0/2}
  }

  // ---- prologue: SU(2) coefs per element, packed f16 (RTN) ----
  unsigned U00[ELEMS], U01[ELEMS];
#pragma unroll
  for (int e = 0; e < ELEMS; ++e) {
    U00[e] = 0u;
    U01[e] = 0u;
    const int wid = wv * ELEMS + e;
    const int widc = wid < batch ? wid : batch - 1;
    if (lane < NA) {
      float xv = x[widc * NA + lane];
      float a = 0.5f * PI_F * atanf(xv);
      float sa, ca;
      sincosf(a, &sa, &ca);
      float u00r = ca * Pr - sa * Qr;
      float u00i = ca * Pi - sa * Qi;
      float u01r = -(sa * Pr + ca * Qr);
      float u01i = -(sa * Pi + ca * Qi);
      U00[e] = pack_h2_rtn(u00r, u00i);
      U01[e] = pack_h2_rtn(u01r, u01i);
    }
  }

  unsigned sv[ELEMS][16];
#pragma unroll
  for (int e = 0; e < ELEMS; ++e) {
#pragma unroll
    for (int r = 0; r < 16; ++r) sv[e][r] = 0u;
    if (lane == 0) sv[e][0] = 0x3C00u;  // (1.0h, 0.0h) -> |0...0>
  }

#pragma unroll 1
  for (int l = 0; l < NL; ++l) {
    const int j0 = l * NQ;
#define GET_U(j)                                         \
  unsigned u00[ELEMS], u01[ELEMS];                       \
  _Pragma("unroll") for (int e = 0; e < ELEMS; ++e) {    \
    u00[e] = readlane_u(U00[e], (j));                    \
    u01[e] = readlane_u(U01[e], (j));                    \
  }
    { GET_U(j0 + 0); cross_gateN<5>(sv, u00, u01, lane); }  // wire0: lane bit5
    { GET_U(j0 + 1); cross_gateN<4>(sv, u00, u01, lane); }  // wire1: lane bit4
    { GET_U(j0 + 2); cross_gateN<3>(sv, u00, u01, lane); }  // wire2: lane bit3
    { GET_U(j0 + 3); cross_gateN<2>(sv, u00, u01, lane); }  // wire3: lane bit2
    { GET_U(j0 + 4); cross_gateN<1>(sv, u00, u01, lane); }  // wire4: lane bit1
    { GET_U(j0 + 5); cross_gateN<0>(sv, u00, u01, lane); }  // wire5: lane bit0
    { GET_U(j0 + 6); local_gateN<3>(sv, u00, u01); }        // wire6: reg bit3
    { GET_U(j0 + 7); local_gateN<2>(sv, u00, u01); }        // wire7: reg bit2
    { GET_U(j0 + 8); local_gateN<1>(sv, u00, u01); }        // wire8: reg bit1
    { GET_U(j0 + 9); local_gateN<0>(sv, u00, u01); }        // wire9: reg bit0
#undef GET_U

    // ---------- CNOT ring, q -> q+1 mod 10, all elements ----------
    // q=0..4 composed: lane gather from gray(lane)
#pragma unroll
    for (int r = 0; r < 16; ++r) {
#pragma unroll
      for (int e = 0; e < ELEMS; ++e)
        sv[e][r] = (unsigned)__shfl((int)sv[e][r], permSrc);
    }
    // q=5: control wire5 = lane bit0, target wire6 = reg bit3 -> cond swap r<->r^8
    {
      const bool c5 = (lane & 1) != 0;
#pragma unroll
      for (int r = 0; r < 8; ++r) {
#pragma unroll
        for (int e = 0; e < ELEMS; ++e) {
          unsigned a = sv[e][r], b = sv[e][r + 8];
          sv[e][r] = c5 ? b : a;
          sv[e][r + 8] = c5 ? a : b;
        }
      }
    }
    // q=6..8 composed: register gather new[j] = old[gray(j)]
#pragma unroll
    for (int e = 0; e < ELEMS; ++e) {
      unsigned t;
      t = sv[e][2]; sv[e][2] = sv[e][3]; sv[e][3] = t;
      t = sv[e][4]; sv[e][4] = sv[e][6]; sv[e][6] = sv[e][5]; sv[e][5] = sv[e][7]; sv[e][7] = t;
      t = sv[e][8]; sv[e][8] = sv[e][12]; sv[e][12] = sv[e][10]; sv[e][10] = sv[e][15]; sv[e][15] = t;
      t = sv[e][9]; sv[e][9] = sv[e][13]; sv[e][13] = sv[e][11]; sv[e][11] = sv[e][14]; sv[e][14] = t;
    }
    // q=9: control wire9 = reg bit0, target wire0 = lane bit5 -> odd r: xor32
#pragma unroll
    for (int r = 1; r < 16; r += 2) {
#pragma unroll
      for (int e = 0; e < ELEMS; ++e)
        sv[e][r] = (unsigned)ishfl_xor<32>((int)sv[e][r]);
    }
  }

  // ---------- epilogue (f32), per element ----------
#pragma unroll
  for (int e = 0; e < ELEMS; ++e) {
    const int wid = wv * ELEMS + e;
    float tot = 0.f, t0 = 0.f, t1 = 0.f, t2 = 0.f, t3 = 0.f;
#pragma unroll
    for (int r = 0; r < 16; ++r) {
      h2 a = __builtin_bit_cast(h2, sv[e][r]);
      float re = (float)a.x, im = (float)a.y;
      float pv = re * re + im * im;
      tot += pv;
      if (r & 1) t0 += pv;
      if (r & 2) t1 += pv;
      if (r & 4) t2 += pv;
      if (r & 8) t3 += pv;
    }
    const float S3 = wave_sum_h(t3);
    const float S2 = wave_sum_h(t2);
    const float S1 = wave_sum_h(t1);
    const float S0 = wave_sum_h(t0);
    // renormalize: true Z = (P0-P1)/(P0+P1) cancels f16 norm drift
    const float N = wave_sum_h(tot);
    const float invN = 1.0f / N;
    // Walsh-Hadamard across lanes: lane L holds sum_i (-1)^popcnt(L&i) tot_i.
    float v = tot, h;
    h = fshfl_xor<1>(v);  v = (lane & 1)  ? h - v : v + h;
    h = fshfl_xor<2>(v);  v = (lane & 2)  ? h - v : v + h;
    h = fshfl_xor<4>(v);  v = (lane & 4)  ? h - v : v + h;
    h = fshfl_xor<8>(v);  v = (lane & 8)  ? h - v : v + h;
    h = fshfl_xor<16>(v); v = (lane & 16) ? h - v : v + h;
    h = fshfl_xor<32>(v); v = (lane & 32) ? h - v : v + h;

    if (wid < batch) {
      float* o = out + wid * NQ;
      if (lane == 32) o[0] = v * invN;  // wire0 sign = lane bit5
      if (lane == 16) o[1] = v * invN;
      if (lane == 8)  o[2] = v * invN;
      if (lane == 4)  o[3] = v * invN;
      if (lane == 2)  o[4] = v * invN;
      if (lane == 1)  o[5] = v * invN;  // wire5 sign = lane bit0
      if (lane == 0) {
        o[6] = (v - 2.f * S3) * invN;  // wire6 = reg bit3; v(lane0) = sum(tot)
        o[7] = (v - 2.f * S2) * invN;
        o[8] = (v - 2.f * S1) * invN;
        o[9] = (v - 2.f * S0) * invN;
      }
    }
  }
}

extern "C" void kernel_launch(void* const* d_in, const int* in_sizes, int n_in,
                              void* d_out, int out_size, void* d_ws, size_t ws_size,
                              hipStream_t stream) {
  const float* x = (const float*)d_in[0];
  const float* w = (const float*)d_in[1];
  float* out = (float*)d_out;
  const int batch = in_sizes[0] / NA;
  const int waves = (batch + ELEMS - 1) / ELEMS;
  const int wavesPerBlock = 4;  // 256 threads
  const int blocks = (waves + wavesPerBlock - 1) / wavesPerBlock;
  qsim_kernel<<<blocks, 256, 0, stream>>>(x, w, out, batch);
}

// Round 11
// 153.855 us; speedup vs baseline: 1.0877x; 1.0877x over previous
//
#include <hip/hip_runtime.h>
#include <hip/hip_fp16.h>
#include <math.h>

#define NQ 10
#define NL 4
#define NA (NQ * NL)
#define PI_F 3.14159265358979323846f

typedef _Float16 h2 __attribute__((ext_vector_type(2)));

// ---------- packed-f16 complex helpers; amp layout: bits[15:0]=re, [31:16]=im ----------
// cmul_sg<SR,SI>(c,s) = (SR*c.re, SI*c.im) complex-multiplied with s. (HW-validated R4/R7)
template <int SR, int SI>
__device__ __forceinline__ unsigned cmul_sg(unsigned c, unsigned s) {
  unsigned d;
  if constexpr (SR > 0) {
    asm("v_pk_mul_f16 %0, %1, %2 op_sel_hi:[0,1]" : "=v"(d) : "v"(c), "v"(s));
  } else {
    asm("v_pk_mul_f16 %0, %1, %2 op_sel_hi:[0,1] neg_lo:[1,0] neg_hi:[1,0]"
        : "=v"(d) : "v"(c), "v"(s));
  }
  if constexpr (SI > 0) {
    asm("v_pk_fma_f16 %0, %1, %2, %0 op_sel:[1,1,0] op_sel_hi:[1,0,1] neg_lo:[1,0,0]"
        : "+v"(d) : "v"(c), "v"(s));
  } else {
    asm("v_pk_fma_f16 %0, %1, %2, %0 op_sel:[1,1,0] op_sel_hi:[1,0,1] neg_hi:[1,0,0]"
        : "+v"(d) : "v"(c), "v"(s));
  }
  return d;
}

template <int SR, int SI>
__device__ __forceinline__ unsigned cfma_sg(unsigned c, unsigned s, unsigned acc) {
  unsigned d;
  if constexpr (SR > 0) {
    asm("v_pk_fma_f16 %0, %1, %2, %3 op_sel_hi:[0,1,1]"
        : "=v"(d) : "v"(c), "v"(s), "v"(acc));
  } else {
    asm("v_pk_fma_f16 %0, %1, %2, %3 op_sel_hi:[0,1,1] neg_lo:[1,0,0] neg_hi:[1,0,0]"
        : "=v"(d) : "v"(c), "v"(s), "v"(acc));
  }
  if constexpr (SI > 0) {
    asm("v_pk_fma_f16 %0, %1, %2, %0 op_sel:[1,1,0] op_sel_hi:[1,0,1] neg_lo:[1,0,0]"
        : "+v"(d) : "v"(c), "v"(s));
  } else {
    asm("v_pk_fma_f16 %0, %1, %2, %0 op_sel:[1,1,0] op_sel_hi:[1,0,1] neg_hi:[1,0,0]"
        : "+v"(d) : "v"(c), "v"(s));
  }
  return d;
}

// ---------- lane-crossing: masks 1,2 quad_perm DPP; 8 row_ror:8 DPP;
// 4,16 ds_swizzle; 32 __shfl_xor (ds_permute). Split keeps VALU/DS balanced. ----------
template <int MASK>
__device__ __forceinline__ int ishfl_xor(int v) {
  if constexpr (MASK == 1) {
    return __builtin_amdgcn_update_dpp(v, v, 0xB1, 0xF, 0xF, true);
  } else if constexpr (MASK == 2) {
    return __builtin_amdgcn_update_dpp(v, v, 0x4E, 0xF, 0xF, true);
  } else if constexpr (MASK == 4) {
    return __builtin_amdgcn_ds_swizzle(v, 0x101F);
  } else if constexpr (MASK == 8) {
    return __builtin_amdgcn_update_dpp(v, v, 0x128, 0xF, 0xF, true);
  } else if constexpr (MASK == 16) {
    return __builtin_amdgcn_ds_swizzle(v, 0x401F);
  } else {
    return __shfl_xor(v, MASK, 64);
  }
}

template <int MASK>
__device__ __forceinline__ float fshfl_xor(float v) {
  return __int_as_float(ishfl_xor<MASK>(__float_as_int(v)));
}

__device__ __forceinline__ unsigned readlane_u(unsigned v, int l) {
  return (unsigned)__builtin_amdgcn_readlane((int)v, l);
}

__device__ __forceinline__ float wave_sum_h(float v) {
  v += fshfl_xor<1>(v);
  v += fshfl_xor<2>(v);
  v += fshfl_xor<4>(v);
  v += fshfl_xor<8>(v);
  v += fshfl_xor<16>(v);
  v += fshfl_xor<32>(v);
  return v;
}

// Round-to-nearest f16 pack (cvt_pkrtz is RTZ -> R6's 1.5% norm contraction).
__device__ __forceinline__ unsigned pack_h2_rtn(float re, float im) {
  return (unsigned)__half_as_ushort(__float2half(re)) |
         ((unsigned)__half_as_ushort(__float2half(im)) << 16);
}

// Cross gate on lane bit LB, both elements interleaved.
// A = bit?conj(u00):u00 (im sign bit31); B = bit?-re(u01):u01 (re sign bit15).
template <int LB>
__device__ __forceinline__ void cross_gate2(unsigned (&sv)[2][16],
                                            const unsigned (&u00)[2],
                                            const unsigned (&u01)[2], int lane) {
  const bool bit = (lane & (1 << LB)) != 0;
  unsigned A[2], B[2];
#pragma unroll
  for (int e = 0; e < 2; ++e) {
    A[e] = bit ? (u00[e] ^ 0x80000000u) : u00[e];
    B[e] = bit ? (u01[e] ^ 0x00008000u) : u01[e];
  }
#pragma unroll
  for (int r = 0; r < 16; ++r) {
    unsigned p0 = (unsigned)ishfl_xor<(1 << LB)>((int)sv[0][r]);
    unsigned p1 = (unsigned)ishfl_xor<(1 << LB)>((int)sv[1][r]);
    sv[0][r] = cfma_sg<1, 1>(B[0], p0, cmul_sg<1, 1>(A[0], sv[0][r]));
    sv[1][r] = cfma_sg<1, 1>(B[1], p1, cmul_sg<1, 1>(A[1], sv[1][r]));
  }
}

// Register-local gate on reg bit RB, both elements interleaved.
template <int RB>
__device__ __forceinline__ void local_gate2(unsigned (&sv)[2][16],
                                            const unsigned (&u00)[2],
                                            const unsigned (&u01)[2]) {
#pragma unroll
  for (int rlo = 0; rlo < 16; ++rlo) {
    if (rlo & (1 << RB)) continue;
    const int rhi = rlo | (1 << RB);
#pragma unroll
    for (int e = 0; e < 2; ++e) {
      unsigned lo = sv[e][rlo], hi = sv[e][rhi];
      sv[e][rlo] = cfma_sg<1, 1>(u01[e], hi, cmul_sg<1, 1>(u00[e], lo));
      sv[e][rhi] = cfma_sg<1, -1>(u00[e], hi, cmul_sg<-1, 1>(u01[e], lo));
    }
  }
}

// One wave = one 64-thread block simulates 2 batch elements (register-
// interleaved). 8192 blocks -> up to 12 waves/SIMD by VGPR (512/40), no
// 4-block residency quantization (R9's (256,4) ran 2 generations, occ 47%).
// State index i = lane*16 + r. Wire q at bit (9-q): wires 0..5 -> lane bits
// 5..0, wires 6..9 -> reg bits 3..0.
// launch_bounds(64,4): 128-VGPR cap — (.,8)'s 64-cap spilled in R8
// (WRITE_SIZE 0.64->27 MB).
__global__ __launch_bounds__(64, 4) void qsim_kernel(
    const float* __restrict__ x, const float* __restrict__ w,
    float* __restrict__ out, int batch) {
  const int lane = threadIdx.x & 63;
  const int wv = blockIdx.x;
  const int permSrc = lane ^ (lane >> 1);  // composed CNOT(q,q+1), q=0..4

  // weight-only gate factors: lane j<40 owns gate j = l*10+q
  float Pr = 0.f, Pi = 0.f, Qr = 0.f, Qi = 0.f;
  if (lane < NA) {
    float w0 = w[2 * lane], w1 = w[2 * lane + 1];
    float sphi, cphi, sw, cw;
    sincosf(0.5f * w0, &sphi, &cphi);
    sincosf(0.5f * w1, &sw, &cw);
    Pr = cw * cphi; Pi = -cw * sphi;  // P = cos(w1/2) e^{-i w0/2}
    Qr = sw * cphi; Qi = sw * sphi;   // Q = sin(w1/2) e^{+i w0/2}
  }

  // ---- prologue for both elements: SU(2) coefs packed f16 (RTN) ----
  unsigned U00[2] = {0u, 0u}, U01[2] = {0u, 0u};
#pragma unroll
  for (int e = 0; e < 2; ++e) {
    const int wid = wv * 2 + e;
    const int widc = wid < batch ? wid : batch - 1;
    if (lane < NA) {
      float xv = x[widc * NA + lane];
      float a = 0.5f * PI_F * atanf(xv);
      float sa, ca;
      sincosf(a, &sa, &ca);
      float u00r = ca * Pr - sa * Qr;
      float u00i = ca * Pi - sa * Qi;
      float u01r = -(sa * Pr + ca * Qr);
      float u01i = -(sa * Pi + ca * Qi);
      U00[e] = pack_h2_rtn(u00r, u00i);
      U01[e] = pack_h2_rtn(u01r, u01i);
    }
  }

  unsigned sv[2][16];
#pragma unroll
  for (int r = 0; r < 16; ++r) { sv[0][r] = 0u; sv[1][r] = 0u; }
  if (lane == 0) { sv[0][0] = 0x3C00u; sv[1][0] = 0x3C00u; }  // |0...0>

#pragma unroll 1
  for (int l = 0; l < NL; ++l) {
    const int j0 = l * NQ;
#define GET_U(j)                                                     \
  const unsigned u00[2] = {readlane_u(U00[0], (j)), readlane_u(U00[1], (j))}; \
  const unsigned u01[2] = {readlane_u(U01[0], (j)), readlane_u(U01[1], (j))}
    { GET_U(j0 + 0); cross_gate2<5>(sv, u00, u01, lane); }  // wire0: lane bit5
    { GET_U(j0 + 1); cross_gate2<4>(sv, u00, u01, lane); }  // wire1: lane bit4
    { GET_U(j0 + 2); cross_gate2<3>(sv, u00, u01, lane); }  // wire2: lane bit3
    { GET_U(j0 + 3); cross_gate2<2>(sv, u00, u01, lane); }  // wire3: lane bit2
    { GET_U(j0 + 4); cross_gate2<1>(sv, u00, u01, lane); }  // wire4: lane bit1
    { GET_U(j0 + 5); cross_gate2<0>(sv, u00, u01, lane); }  // wire5: lane bit0
    { GET_U(j0 + 6); local_gate2<3>(sv, u00, u01); }        // wire6: reg bit3
    { GET_U(j0 + 7); local_gate2<2>(sv, u00, u01); }        // wire7: reg bit2
    { GET_U(j0 + 8); local_gate2<1>(sv, u00, u01); }        // wire8: reg bit1
    { GET_U(j0 + 9); local_gate2<0>(sv, u00, u01); }        // wire9: reg bit0
#undef GET_U

    // ---------- CNOT ring, q -> q+1 mod 10, both elements ----------
    // q=0..4 composed: lane gather from gray(lane)
#pragma unroll
    for (int r = 0; r < 16; ++r) {
      sv[0][r] = (unsigned)__shfl((int)sv[0][r], permSrc);
      sv[1][r] = (unsigned)__shfl((int)sv[1][r], permSrc);
    }
    // q=5: control wire5 = lane bit0, target wire6 = reg bit3 -> cond swap r<->r^8
    {
      const bool c5 = (lane & 1) != 0;
#pragma unroll
      for (int r = 0; r < 8; ++r) {
#pragma unroll
        for (int e = 0; e < 2; ++e) {
          unsigned a = sv[e][r], b = sv[e][r + 8];
          sv[e][r] = c5 ? b : a;
          sv[e][r + 8] = c5 ? a : b;
        }
      }
    }
    // q=6..8 composed: register gather new[j] = old[gray(j)]
#pragma unroll
    for (int e = 0; e < 2; ++e) {
      unsigned t;
      t = sv[e][2]; sv[e][2] = sv[e][3]; sv[e][3] = t;
      t = sv[e][4]; sv[e][4] = sv[e][6]; sv[e][6] = sv[e][5]; sv[e][5] = sv[e][7]; sv[e][7] = t;
      t = sv[e][8]; sv[e][8] = sv[e][12]; sv[e][12] = sv[e][10]; sv[e][10] = sv[e][15]; sv[e][15] = t;
      t = sv[e][9]; sv[e][9] = sv[e][13]; sv[e][13] = sv[e][11]; sv[e][11] = sv[e][14]; sv[e][14] = t;
    }
    // q=9: control wire9 = reg bit0, target wire0 = lane bit5 -> odd r: xor32
#pragma unroll
    for (int r = 1; r < 16; r += 2) {
      sv[0][r] = (unsigned)ishfl_xor<32>((int)sv[0][r]);
      sv[1][r] = (unsigned)ishfl_xor<32>((int)sv[1][r]);
    }
  }

  // ---------- epilogue (f32), per element ----------
#pragma unroll
  for (int e = 0; e < 2; ++e) {
    const int wid = wv * 2 + e;
    float tot = 0.f, t0 = 0.f, t1 = 0.f, t2 = 0.f, t3 = 0.f;
#pragma unroll
    for (int r = 0; r < 16; ++r) {
      h2 a = __builtin_bit_cast(h2, sv[e][r]);
      float re = (float)a.x, im = (float)a.y;
      float pv = re * re + im * im;
      tot += pv;
      if (r & 1) t0 += pv;
      if (r & 2) t1 += pv;
      if (r & 4) t2 += pv;
      if (r & 8) t3 += pv;
    }
    const float S3 = wave_sum_h(t3);
    const float S2 = wave_sum_h(t2);
    const float S1 = wave_sum_h(t1);
    const float S0 = wave_sum_h(t0);
    // renormalize: true Z = (P0-P1)/(P0+P1) cancels f16 norm drift
    const float N = wave_sum_h(tot);
    const float invN = 1.0f / N;
    // Walsh-Hadamard across lanes: lane L holds sum_i (-1)^popcnt(L&i) tot_i.
    float v = tot, h;
    h = fshfl_xor<1>(v);  v = (lane & 1)  ? h - v : v + h;
    h = fshfl_xor<2>(v);  v = (lane & 2)  ? h - v : v + h;
    h = fshfl_xor<4>(v);  v = (lane & 4)  ? h - v : v + h;
    h = fshfl_xor<8>(v);  v = (lane & 8)  ? h - v : v + h;
    h = fshfl_xor<16>(v); v = (lane & 16) ? h - v : v + h;
    h = fshfl_xor<32>(v); v = (lane & 32) ? h - v : v + h;

    if (wid < batch) {
      float* o = out + wid * NQ;
      if (lane == 32) o[0] = v * invN;  // wire0 sign = lane bit5
      if (lane == 16) o[1] = v * invN;
      if (lane == 8)  o[2] = v * invN;
      if (lane == 4)  o[3] = v * invN;
      if (lane == 2)  o[4] = v * invN;
      if (lane == 1)  o[5] = v * invN;  // wire5 sign = lane bit0
      if (lane == 0) {
        o[6] = (v - 2.f * S3) * invN;  // wire6 = reg bit3; v(lane0) = sum(tot)
        o[7] = (v - 2.f * S2) * invN;
        o[8] = (v - 2.f * S1) * invN;
        o[9] = (v - 2.f * S0) * invN;
      }
    }
  }
}

extern "C" void kernel_launch(void* const* d_in, const int* in_sizes, int n_in,
                              void* d_out, int out_size, void* d_ws, size_t ws_size,
                              hipStream_t stream) {
  const float* x = (const float*)d_in[0];
  const float* w = (const float*)d_in[1];
  float* out = (float*)d_out;
  const int batch = in_sizes[0] / NA;
  const int blocks = (batch + 1) / 2;  // 2 elements per 64-thread block (1 wave)
  qsim_kernel<<<blocks, 64, 0, stream>>>(x, w, out, batch);
}

// Round 12
// 135.519 us; speedup vs baseline: 1.2349x; 1.1353x over previous
//
#include <hip/hip_runtime.h>
#include <hip/hip_fp16.h>
#include <math.h>

#define NQ 10
#define NL 4
#define NA (NQ * NL)
#define PI_F 3.14159265358979323846f

typedef _Float16 h2 __attribute__((ext_vector_type(2)));

// ---------- packed-f16 complex helpers; amp layout: bits[15:0]=re, [31:16]=im ----------
// cmul_sg<SR,SI>(c,s) = (SR*c.re, SI*c.im) complex-multiplied with s. (HW-validated R4/R7)
template <int SR, int SI>
__device__ __forceinline__ unsigned cmul_sg(unsigned c, unsigned s) {
  unsigned d;
  if constexpr (SR > 0) {
    asm("v_pk_mul_f16 %0, %1, %2 op_sel_hi:[0,1]" : "=v"(d) : "v"(c), "v"(s));
  } else {
    asm("v_pk_mul_f16 %0, %1, %2 op_sel_hi:[0,1] neg_lo:[1,0] neg_hi:[1,0]"
        : "=v"(d) : "v"(c), "v"(s));
  }
  if constexpr (SI > 0) {
    asm("v_pk_fma_f16 %0, %1, %2, %0 op_sel:[1,1,0] op_sel_hi:[1,0,1] neg_lo:[1,0,0]"
        : "+v"(d) : "v"(c), "v"(s));
  } else {
    asm("v_pk_fma_f16 %0, %1, %2, %0 op_sel:[1,1,0] op_sel_hi:[1,0,1] neg_hi:[1,0,0]"
        : "+v"(d) : "v"(c), "v"(s));
  }
  return d;
}

template <int SR, int SI>
__device__ __forceinline__ unsigned cfma_sg(unsigned c, unsigned s, unsigned acc) {
  unsigned d;
  if constexpr (SR > 0) {
    asm("v_pk_fma_f16 %0, %1, %2, %3 op_sel_hi:[0,1,1]"
        : "=v"(d) : "v"(c), "v"(s), "v"(acc));
  } else {
    asm("v_pk_fma_f16 %0, %1, %2, %3 op_sel_hi:[0,1,1] neg_lo:[1,0,0] neg_hi:[1,0,0]"
        : "=v"(d) : "v"(c), "v"(s), "v"(acc));
  }
  if constexpr (SI > 0) {
    asm("v_pk_fma_f16 %0, %1, %2, %0 op_sel:[1,1,0] op_sel_hi:[1,0,1] neg_lo:[1,0,0]"
        : "+v"(d) : "v"(c), "v"(s));
  } else {
    asm("v_pk_fma_f16 %0, %1, %2, %0 op_sel:[1,1,0] op_sel_hi:[1,0,1] neg_hi:[1,0,0]"
        : "+v"(d) : "v"(c), "v"(s));
  }
  return d;
}

// ---------- lane-crossing: masks 1,2 quad_perm DPP; 8 row_ror:8 DPP;
// 4,16 ds_swizzle; 32 __shfl_xor (ds_permute). Split keeps VALU/DS balanced. ----------
template <int MASK>
__device__ __forceinline__ int ishfl_xor(int v) {
  if constexpr (MASK == 1) {
    return __builtin_amdgcn_update_dpp(v, v, 0xB1, 0xF, 0xF, true);
  } else if constexpr (MASK == 2) {
    return __builtin_amdgcn_update_dpp(v, v, 0x4E, 0xF, 0xF, true);
  } else if constexpr (MASK == 4) {
    return __builtin_amdgcn_ds_swizzle(v, 0x101F);
  } else if constexpr (MASK == 8) {
    return __builtin_amdgcn_update_dpp(v, v, 0x128, 0xF, 0xF, true);
  } else if constexpr (MASK == 16) {
    return __builtin_amdgcn_ds_swizzle(v, 0x401F);
  } else {
    return __shfl_xor(v, MASK, 64);
  }
}

template <int MASK>
__device__ __forceinline__ float fshfl_xor(float v) {
  return __int_as_float(ishfl_xor<MASK>(__float_as_int(v)));
}

__device__ __forceinline__ unsigned readlane_u(unsigned v, int l) {
  return (unsigned)__builtin_amdgcn_readlane((int)v, l);
}

__device__ __forceinline__ float wave_sum_h(float v) {
  v += fshfl_xor<1>(v);
  v += fshfl_xor<2>(v);
  v += fshfl_xor<4>(v);
  v += fshfl_xor<8>(v);
  v += fshfl_xor<16>(v);
  v += fshfl_xor<32>(v);
  return v;
}

// Round-to-nearest f16 pack (cvt_pkrtz is RTZ -> R6's 1.5% norm contraction).
__device__ __forceinline__ unsigned pack_h2_rtn(float re, float im) {
  return (unsigned)__half_as_ushort(__float2half(re)) |
         ((unsigned)__half_as_ushort(__float2half(im)) << 16);
}

// Cross gate on lane bit LB, both elements, full 16 regs.
template <int LB>
__device__ __forceinline__ void cross_gate2(unsigned (&sv)[2][16],
                                            const unsigned (&u00)[2],
                                            const unsigned (&u01)[2], int lane) {
  const bool bit = (lane & (1 << LB)) != 0;
  unsigned A[2], B[2];
#pragma unroll
  for (int e = 0; e < 2; ++e) {
    A[e] = bit ? (u00[e] ^ 0x80000000u) : u00[e];
    B[e] = bit ? (u01[e] ^ 0x00008000u) : u01[e];
  }
#pragma unroll
  for (int r = 0; r < 16; ++r) {
    unsigned p0 = (unsigned)ishfl_xor<(1 << LB)>((int)sv[0][r]);
    unsigned p1 = (unsigned)ishfl_xor<(1 << LB)>((int)sv[1][r]);
    sv[0][r] = cfma_sg<1, 1>(B[0], p0, cmul_sg<1, 1>(A[0], sv[0][r]));
    sv[1][r] = cfma_sg<1, 1>(B[1], p1, cmul_sg<1, 1>(A[1], sv[1][r]));
  }
}

// Layer-0 cross gate: regs 1..15 are exactly zero, only r=0 carries amplitude.
template <int LB>
__device__ __forceinline__ void cross_gate2_r0(unsigned (&sv)[2][16],
                                               const unsigned (&u00)[2],
                                               const unsigned (&u01)[2], int lane) {
  const bool bit = (lane & (1 << LB)) != 0;
#pragma unroll
  for (int e = 0; e < 2; ++e) {
    const unsigned A = bit ? (u00[e] ^ 0x80000000u) : u00[e];
    const unsigned B = bit ? (u01[e] ^ 0x00008000u) : u01[e];
    unsigned p = (unsigned)ishfl_xor<(1 << LB)>((int)sv[e][0]);
    sv[e][0] = cfma_sg<1, 1>(B, p, cmul_sg<1, 1>(A, sv[e][0]));
  }
}

// Register-local gate on reg bit RB, full (both pair halves nonzero).
template <int RB>
__device__ __forceinline__ void local_gate2(unsigned (&sv)[2][16],
                                            const unsigned (&u00)[2],
                                            const unsigned (&u01)[2]) {
#pragma unroll
  for (int rlo = 0; rlo < 16; ++rlo) {
    if (rlo & (1 << RB)) continue;
    const int rhi = rlo | (1 << RB);
#pragma unroll
    for (int e = 0; e < 2; ++e) {
      unsigned lo = sv[e][rlo], hi = sv[e][rhi];
      sv[e][rlo] = cfma_sg<1, 1>(u01[e], hi, cmul_sg<1, 1>(u00[e], lo));
      sv[e][rhi] = cfma_sg<1, -1>(u00[e], hi, cmul_sg<-1, 1>(u01[e], lo));
    }
  }
}

// Layer-0 local gate: live regs before gate RB are {r : r & ((2<<RB)-1) == 0};
// hi half of every pair is exactly zero -> pure cmul fill (2 pk each).
// lo' = u00*lo ; hi' = -conj(u01)*lo.
template <int RB>
__device__ __forceinline__ void local_gate2_fill(unsigned (&sv)[2][16],
                                                 const unsigned (&u00)[2],
                                                 const unsigned (&u01)[2]) {
#pragma unroll
  for (int rlo = 0; rlo < 16; ++rlo) {
    if (rlo & ((2 << RB) - 1)) continue;  // only live, pair-base regs
    const int rhi = rlo | (1 << RB);
#pragma unroll
    for (int e = 0; e < 2; ++e) {
      unsigned lo = sv[e][rlo];
      sv[e][rhi] = cmul_sg<-1, 1>(u01[e], lo);
      sv[e][rlo] = cmul_sg<1, 1>(u00[e], lo);
    }
  }
}

// CNOT ring, q -> q+1 mod 10 (composed), both elements.
__device__ __forceinline__ void ring_step(unsigned (&sv)[2][16], int lane,
                                          int permSrc) {
  // q=0..4 composed: lane gather from gray(lane)
#pragma unroll
  for (int r = 0; r < 16; ++r) {
    sv[0][r] = (unsigned)__shfl((int)sv[0][r], permSrc);
    sv[1][r] = (unsigned)__shfl((int)sv[1][r], permSrc);
  }
  // q=5: control wire5 = lane bit0, target wire6 = reg bit3 -> cond swap r<->r^8
  {
    const bool c5 = (lane & 1) != 0;
#pragma unroll
    for (int r = 0; r < 8; ++r) {
#pragma unroll
      for (int e = 0; e < 2; ++e) {
        unsigned a = sv[e][r], b = sv[e][r + 8];
        sv[e][r] = c5 ? b : a;
        sv[e][r + 8] = c5 ? a : b;
      }
    }
  }
  // q=6..8 composed: register gather new[j] = old[gray(j)]
#pragma unroll
  for (int e = 0; e < 2; ++e) {
    unsigned t;
    t = sv[e][2]; sv[e][2] = sv[e][3]; sv[e][3] = t;
    t = sv[e][4]; sv[e][4] = sv[e][6]; sv[e][6] = sv[e][5]; sv[e][5] = sv[e][7]; sv[e][7] = t;
    t = sv[e][8]; sv[e][8] = sv[e][12]; sv[e][12] = sv[e][10]; sv[e][10] = sv[e][15]; sv[e][15] = t;
    t = sv[e][9]; sv[e][9] = sv[e][13]; sv[e][13] = sv[e][11]; sv[e][11] = sv[e][14]; sv[e][14] = t;
  }
  // q=9: control wire9 = reg bit0, target wire0 = lane bit5 -> odd r: xor32
#pragma unroll
  for (int r = 1; r < 16; r += 2) {
    sv[0][r] = (unsigned)ishfl_xor<32>((int)sv[0][r]);
    sv[1][r] = (unsigned)ishfl_xor<32>((int)sv[1][r]);
  }
}

// One wave = one 64-thread block simulates 2 batch elements (register-
// interleaved). State index i = lane*16 + r. Wire q at bit (9-q): wires
// 0..5 -> lane bits 5..0, wires 6..9 -> reg bits 3..0.
// Layer 0 runs a sparsity-specialized path (|0...0> start: regs 1..15 are
// exact zeros through the cross gates; local gates fill 1->2->4->8->16 live
// regs) — bit-identical results, ~22% fewer pk instructions.
// launch_bounds(64,4): 128-VGPR cap — (.,8)'s 64-cap spilled in R8.
__global__ __launch_bounds__(64, 4) void qsim_kernel(
    const float* __restrict__ x, const float* __restrict__ w,
    float* __restrict__ out, int batch) {
  const int lane = threadIdx.x & 63;
  const int wv = blockIdx.x;
  const int permSrc = lane ^ (lane >> 1);  // composed CNOT(q,q+1), q=0..4

  // weight-only gate factors: lane j<40 owns gate j = l*10+q
  float Pr = 0.f, Pi = 0.f, Qr = 0.f, Qi = 0.f;
  if (lane < NA) {
    float w0 = w[2 * lane], w1 = w[2 * lane + 1];
    float sphi, cphi, sw, cw;
    sincosf(0.5f * w0, &sphi, &cphi);
    sincosf(0.5f * w1, &sw, &cw);
    Pr = cw * cphi; Pi = -cw * sphi;  // P = cos(w1/2) e^{-i w0/2}
    Qr = sw * cphi; Qi = sw * sphi;   // Q = sin(w1/2) e^{+i w0/2}
  }

  // ---- prologue for both elements: SU(2) coefs packed f16 (RTN) ----
  unsigned U00[2] = {0u, 0u}, U01[2] = {0u, 0u};
#pragma unroll
  for (int e = 0; e < 2; ++e) {
    const int wid = wv * 2 + e;
    const int widc = wid < batch ? wid : batch - 1;
    if (lane < NA) {
      float xv = x[widc * NA + lane];
      float a = 0.5f * PI_F * atanf(xv);
      float sa, ca;
      sincosf(a, &sa, &ca);
      float u00r = ca * Pr - sa * Qr;
      float u00i = ca * Pi - sa * Qi;
      float u01r = -(sa * Pr + ca * Qr);
      float u01i = -(sa * Pi + ca * Qi);
      U00[e] = pack_h2_rtn(u00r, u00i);
      U01[e] = pack_h2_rtn(u01r, u01i);
    }
  }

  unsigned sv[2][16];
#pragma unroll
  for (int r = 0; r < 16; ++r) { sv[0][r] = 0u; sv[1][r] = 0u; }
  if (lane == 0) { sv[0][0] = 0x3C00u; sv[1][0] = 0x3C00u; }  // |0...0>

#define GET_U(j)                                                     \
  const unsigned u00[2] = {readlane_u(U00[0], (j)), readlane_u(U00[1], (j))}; \
  const unsigned u01[2] = {readlane_u(U01[0], (j)), readlane_u(U01[1], (j))}

  // ---------- layer 0: sparsity-specialized ----------
  { GET_U(0); cross_gate2_r0<5>(sv, u00, u01, lane); }  // wire0
  { GET_U(1); cross_gate2_r0<4>(sv, u00, u01, lane); }  // wire1
  { GET_U(2); cross_gate2_r0<3>(sv, u00, u01, lane); }  // wire2
  { GET_U(3); cross_gate2_r0<2>(sv, u00, u01, lane); }  // wire3
  { GET_U(4); cross_gate2_r0<1>(sv, u00, u01, lane); }  // wire4
  { GET_U(5); cross_gate2_r0<0>(sv, u00, u01, lane); }  // wire5
  { GET_U(6); local_gate2_fill<3>(sv, u00, u01); }      // wire6: 1 -> 2 live
  { GET_U(7); local_gate2_fill<2>(sv, u00, u01); }      // wire7: 2 -> 4
  { GET_U(8); local_gate2_fill<1>(sv, u00, u01); }      // wire8: 4 -> 8
  { GET_U(9); local_gate2_fill<0>(sv, u00, u01); }      // wire9: 8 -> 16
  ring_step(sv, lane, permSrc);

  // ---------- layers 1..3: dense ----------
#pragma unroll 1
  for (int l = 1; l < NL; ++l) {
    const int j0 = l * NQ;
    { GET_U(j0 + 0); cross_gate2<5>(sv, u00, u01, lane); }  // wire0: lane bit5
    { GET_U(j0 + 1); cross_gate2<4>(sv, u00, u01, lane); }  // wire1: lane bit4
    { GET_U(j0 + 2); cross_gate2<3>(sv, u00, u01, lane); }  // wire2: lane bit3
    { GET_U(j0 + 3); cross_gate2<2>(sv, u00, u01, lane); }  // wire3: lane bit2
    { GET_U(j0 + 4); cross_gate2<1>(sv, u00, u01, lane); }  // wire4: lane bit1
    { GET_U(j0 + 5); cross_gate2<0>(sv, u00, u01, lane); }  // wire5: lane bit0
    { GET_U(j0 + 6); local_gate2<3>(sv, u00, u01); }        // wire6: reg bit3
    { GET_U(j0 + 7); local_gate2<2>(sv, u00, u01); }        // wire7: reg bit2
    { GET_U(j0 + 8); local_gate2<1>(sv, u00, u01); }        // wire8: reg bit1
    { GET_U(j0 + 9); local_gate2<0>(sv, u00, u01); }        // wire9: reg bit0
    ring_step(sv, lane, permSrc);
  }
#undef GET_U

  // ---------- epilogue (f32), per element ----------
#pragma unroll
  for (int e = 0; e < 2; ++e) {
    const int wid = wv * 2 + e;
    float tot = 0.f, t0 = 0.f, t1 = 0.f, t2 = 0.f, t3 = 0.f;
#pragma unroll
    for (int r = 0; r < 16; ++r) {
      h2 a = __builtin_bit_cast(h2, sv[e][r]);
      float re = (float)a.x, im = (float)a.y;
      float pv = re * re + im * im;
      tot += pv;
      if (r & 1) t0 += pv;
      if (r & 2) t1 += pv;
      if (r & 4) t2 += pv;
      if (r & 8) t3 += pv;
    }
    const float S3 = wave_sum_h(t3);
    const float S2 = wave_sum_h(t2);
    const float S1 = wave_sum_h(t1);
    const float S0 = wave_sum_h(t0);
    // renormalize: true Z = (P0-P1)/(P0+P1) cancels f16 norm drift
    const float N = wave_sum_h(tot);
    const float invN = 1.0f / N;
    // Walsh-Hadamard across lanes: lane L holds sum_i (-1)^popcnt(L&i) tot_i.
    float v = tot, h;
    h = fshfl_xor<1>(v);  v = (lane & 1)  ? h - v : v + h;
    h = fshfl_xor<2>(v);  v = (lane & 2)  ? h - v : v + h;
    h = fshfl_xor<4>(v);  v = (lane & 4)  ? h - v : v + h;
    h = fshfl_xor<8>(v);  v = (lane & 8)  ? h - v : v + h;
    h = fshfl_xor<16>(v); v = (lane & 16) ? h - v : v + h;
    h = fshfl_xor<32>(v); v = (lane & 32) ? h - v : v + h;

    if (wid < batch) {
      float* o = out + wid * NQ;
      if (lane == 32) o[0] = v * invN;  // wire0 sign = lane bit5
      if (lane == 16) o[1] = v * invN;
      if (lane == 8)  o[2] = v * invN;
      if (lane == 4)  o[3] = v * invN;
      if (lane == 2)  o[4] = v * invN;
      if (lane == 1)  o[5] = v * invN;  // wire5 sign = lane bit0
      if (lane == 0) {
        o[6] = (v - 2.f * S3) * invN;  // wire6 = reg bit3; v(lane0) = sum(tot)
        o[7] = (v - 2.f * S2) * invN;
        o[8] = (v - 2.f * S1) * invN;
        o[9] = (v - 2.f * S0) * invN;
      }
    }
  }
}

extern "C" void kernel_launch(void* const* d_in, const int* in_sizes, int n_in,
                              void* d_out, int out_size, void* d_ws, size_t ws_size,
                              hipStream_t stream) {
  const float* x = (const float*)d_in[0];
  const float* w = (const float*)d_in[1];
  float* out = (float*)d_out;
  const int batch = in_sizes[0] / NA;
  const int blocks = (batch + 1) / 2;  // 2 elements per 64-thread block (1 wave)
  qsim_kernel<<<blocks, 64, 0, stream>>>(x, w, out, batch);
}